// Round 11
// baseline (458.666 us; speedup 1.0000x reference)
//
#include <hip/hip_runtime.h>
#include <math.h>

#define WAVE 64

typedef __attribute__((ext_vector_type(4))) float f32x4;
typedef _Float16 h16x4 __attribute__((ext_vector_type(4)));
typedef _Float16 h16x8 __attribute__((ext_vector_type(8)));

// ---------------- fused front: count | cvt16 | cvt_w_all | bounds ----------------
__global__ __launch_bounds__(256)
void k_front(const int* __restrict__ ei, int E, int N, int* __restrict__ cnt,
             const float* __restrict__ x, _Float16* __restrict__ hB,
             const float* __restrict__ W0, const float* __restrict__ W1,
             const float* __restrict__ W2, const float* __restrict__ W3,
             _Float16* __restrict__ Wh,
             const int* __restrict__ batch, int B, int* __restrict__ bs,
             int CB, int XB, int WB){
  int bid = blockIdx.x, t = threadIdx.x;
  if (bid < CB){
    int i = bid*256 + t;
    if (i < E + N){
      int d = (i < E) ? ei[E + i] : (i - E);
      atomicAdd(&cnt[d], 1);
    }
  } else if (bid < CB + XB){
    int i = (bid - CB)*256 + t;
    if (i < N*32){
      float4 v = ((const float4*)x)[i];
      h16x4 o;
      o[0] = (_Float16)v.x; o[1] = (_Float16)v.y;
      o[2] = (_Float16)v.z; o[3] = (_Float16)v.w;
      ((h16x4*)hB)[i] = o;
    }
  } else if (bid < CB + XB + WB){
    int i = (bid - CB - XB)*256 + t;
    if (i < 32768){                       // L1: K=128, Nc=256
      int k = i >> 8, n = i & 255;
      Wh[(size_t)n*128 + k] = (_Float16)W0[i];
    } else if (i < 98304){                // L2
      int j = i - 32768; int k = j >> 8, n = j & 255;
      Wh[32768 + (size_t)n*256 + k] = (_Float16)W1[j];
    } else if (i < 163840){               // L3
      int j = i - 98304; int k = j >> 8, n = j & 255;
      Wh[98304 + (size_t)n*256 + k] = (_Float16)W2[j];
    } else if (i < 294912){               // L4: K=256, Nc=512
      int j = i - 163840; int k = j >> 9, n = j & 511;
      Wh[163840 + (size_t)n*256 + k] = (_Float16)W3[j];
    }
  } else {
    int b = t;
    if (b <= B){
      int lo = 0, hi = N;
      while (lo < hi){ int mid = (lo + hi) >> 1; if (batch[mid] < b) lo = mid + 1; else hi = mid; }
      bs[b] = lo;
    }
  }
}

// ---------------- scan1 with fused block-sum scan (last-block pattern) ----------------
__global__ __launch_bounds__(1024)
void k_scan1(const int* __restrict__ cnt, int* __restrict__ rp, int* __restrict__ bsum,
             int* __restrict__ done, int N, int nb){
  __shared__ int sd[1024];
  int t = threadIdx.x, i = blockIdx.x*1024 + t;
  int v = (i < N) ? cnt[i] : 0;
  sd[t] = v;
  __syncthreads();
  for (int off = 1; off < 1024; off <<= 1){
    int x = (t >= off) ? sd[t-off] : 0;
    __syncthreads();
    sd[t] += x;
    __syncthreads();
  }
  if (i < N) rp[i] = sd[t] - v;
  if (t == 1023) bsum[blockIdx.x] = sd[1023];
  __threadfence();
  __syncthreads();
  if (t == 0){
    if (atomicAdd(done, 1) == nb - 1){
      int run = 0;
      for (int b2 = 0; b2 < nb; ++b2){ int s = bsum[b2]; bsum[b2] = run; run += s; }
      rp[N] = run;
    }
  }
}

__global__ __launch_bounds__(1024)
void k_scan3(int* __restrict__ rp, int* __restrict__ cur, const int* __restrict__ bsum, int N){
  int i = blockIdx.x*1024 + threadIdx.x;
  if (i < N){
    int v = rp[i] + bsum[blockIdx.x];
    rp[i] = v;
    cur[i] = v;
  }
}

__global__ void k_fill(const int* __restrict__ ei, int E, int N,
                       int* __restrict__ cur, int* __restrict__ es){
  int i = blockIdx.x*blockDim.x + threadIdx.x;
  if (i >= E + N) return;
  int s, d;
  if (i < E){ s = ei[i]; d = ei[E + i]; } else { s = d = i - E; }
  int pos = atomicAdd(&cur[d], 1);
  es[pos] = s;
}

// ---------------- fp16 MFMA GEMM (64x128 tile, 4 waves, dbuf LDS), fused alpha ----------------
template<int CHEAD>
__global__ __launch_bounds__(256)
void k_gemm_fused(const _Float16* __restrict__ Ax, const _Float16* __restrict__ Bw,
                  _Float16* __restrict__ Ch,
                  const float* __restrict__ asr, const float* __restrict__ adt,
                  float* __restrict__ as4, float* __restrict__ ad4,
                  int M, int K, int Nc){
  constexpr int LDP = 40;
  __shared__ _Float16 sA[2][64*LDP], sB[2][128*LDP];   // 10 KB + 20.5 KB
  const int tid = threadIdx.x;
  const int m0 = blockIdx.x*64, n0 = blockIdx.y*128;
  const int w = tid >> 6, l = tid & 63;
  const int wr = w >> 1, wc = w & 1;          // 2M x 2N waves
  const int sr = tid >> 2, sc = (tid & 3)*8;  // 64 rows x 4 thr/row x 8 halves

  f32x4 acc00={0.f,0.f,0.f,0.f}, acc01=acc00, acc02=acc00, acc03=acc00;
  f32x4 acc10=acc00, acc11=acc00, acc12=acc00, acc13=acc00;

  const int arow = m0 + sr;
  const bool aval = arow < M;
  const size_t aoff  = (size_t)arow*K + sc;
  const size_t boff0 = (size_t)(n0 + sr)*K + sc;
  const size_t boff1 = (size_t)(n0 + 64 + sr)*K + sc;

  const int fa0 = (wr*32 + (l & 15))*LDP + (l >> 4)*8;
  const int fa1 = fa0 + 16*LDP;
  const int fb0 = (wc*64 + (l & 15))*LDP + (l >> 4)*8;
  const int steps = K >> 5;

  uint4 va = make_uint4(0,0,0,0), vb0, vb1;
  if (aval) va = *(const uint4*)(Ax + aoff);
  vb0 = *(const uint4*)(Bw + boff0);
  vb1 = *(const uint4*)(Bw + boff1);
  *(uint4*)&sA[0][sr*LDP + sc] = va;
  *(uint4*)&sB[0][sr*LDP + sc] = vb0;
  *(uint4*)&sB[0][(64 + sr)*LDP + sc] = vb1;
  __syncthreads();

  for (int ks = 0; ks < steps; ++ks){
    const int cur = ks & 1;
    const bool more = (ks + 1 < steps);
    if (more){
      const int k0 = (ks + 1)*32;
      va = make_uint4(0,0,0,0);
      if (aval) va = *(const uint4*)(Ax + aoff + k0);
      vb0 = *(const uint4*)(Bw + boff0 + k0);
      vb1 = *(const uint4*)(Bw + boff1 + k0);
    }

    h16x8 a0 = *(const h16x8*)&sA[cur][fa0];
    h16x8 a1 = *(const h16x8*)&sA[cur][fa1];
    h16x8 b;
    b = *(const h16x8*)&sB[cur][fb0];
    acc00 = __builtin_amdgcn_mfma_f32_16x16x32_f16(a0, b, acc00, 0, 0, 0);
    acc10 = __builtin_amdgcn_mfma_f32_16x16x32_f16(a1, b, acc10, 0, 0, 0);
    b = *(const h16x8*)&sB[cur][fb0 + 16*LDP];
    acc01 = __builtin_amdgcn_mfma_f32_16x16x32_f16(a0, b, acc01, 0, 0, 0);
    acc11 = __builtin_amdgcn_mfma_f32_16x16x32_f16(a1, b, acc11, 0, 0, 0);
    b = *(const h16x8*)&sB[cur][fb0 + 32*LDP];
    acc02 = __builtin_amdgcn_mfma_f32_16x16x32_f16(a0, b, acc02, 0, 0, 0);
    acc12 = __builtin_amdgcn_mfma_f32_16x16x32_f16(a1, b, acc12, 0, 0, 0);
    b = *(const h16x8*)&sB[cur][fb0 + 48*LDP];
    acc03 = __builtin_amdgcn_mfma_f32_16x16x32_f16(a0, b, acc03, 0, 0, 0);
    acc13 = __builtin_amdgcn_mfma_f32_16x16x32_f16(a1, b, acc13, 0, 0, 0);

    if (more){
      *(uint4*)&sA[cur^1][sr*LDP + sc] = va;
      *(uint4*)&sB[cur^1][sr*LDP + sc] = vb0;
      *(uint4*)&sB[cur^1][(64 + sr)*LDP + sc] = vb1;
      __syncthreads();
    }
  }

  // C/D layout per 16x16 frag: col = lane&15, row = (lane>>4)*4 + j
  const int colb = n0 + wc*64 + (l & 15);
  const float ca0 = asr[colb], ca1 = asr[colb+16], ca2 = asr[colb+32], ca3 = asr[colb+48];
  const float cd0 = adt[colb], cd1 = adt[colb+16], cd2 = adt[colb+32], cd3 = adt[colb+48];

  float psm0[4], pdm0[4], psm1[4], pdm1[4];   // compile-time unrolled only
  {
    const int rb = m0 + wr*32 + (l >> 4)*4;
    #pragma unroll
    for (int j = 0; j < 4; ++j){
      int row = rb + j;
      if (row < M){
        _Float16* hp = Ch + (size_t)row*Nc + colb;
        hp[0]  = (_Float16)acc00[j];
        hp[16] = (_Float16)acc01[j];
        hp[32] = (_Float16)acc02[j];
        hp[48] = (_Float16)acc03[j];
      }
      float ps = ca0*acc00[j] + ca1*acc01[j] + ca2*acc02[j] + ca3*acc03[j];
      float pd = cd0*acc00[j] + cd1*acc01[j] + cd2*acc02[j] + cd3*acc03[j];
      ps += __shfl_xor(ps, 1, WAVE);  pd += __shfl_xor(pd, 1, WAVE);
      ps += __shfl_xor(ps, 2, WAVE);  pd += __shfl_xor(pd, 2, WAVE);
      ps += __shfl_xor(ps, 4, WAVE);  pd += __shfl_xor(pd, 4, WAVE);
      ps += __shfl_xor(ps, 8, WAVE);  pd += __shfl_xor(pd, 8, WAVE);
      psm0[j] = ps; pdm0[j] = pd;
    }
  }
  {
    const int rb = m0 + wr*32 + 16 + (l >> 4)*4;
    #pragma unroll
    for (int j = 0; j < 4; ++j){
      int row = rb + j;
      if (row < M){
        _Float16* hp = Ch + (size_t)row*Nc + colb;
        hp[0]  = (_Float16)acc10[j];
        hp[16] = (_Float16)acc11[j];
        hp[32] = (_Float16)acc12[j];
        hp[48] = (_Float16)acc13[j];
      }
      float ps = ca0*acc10[j] + ca1*acc11[j] + ca2*acc12[j] + ca3*acc13[j];
      float pd = cd0*acc10[j] + cd1*acc11[j] + cd2*acc12[j] + cd3*acc13[j];
      ps += __shfl_xor(ps, 1, WAVE);  pd += __shfl_xor(pd, 1, WAVE);
      ps += __shfl_xor(ps, 2, WAVE);  pd += __shfl_xor(pd, 2, WAVE);
      ps += __shfl_xor(ps, 4, WAVE);  pd += __shfl_xor(pd, 4, WAVE);
      ps += __shfl_xor(ps, 8, WAVE);  pd += __shfl_xor(pd, 8, WAVE);
      psm1[j] = ps; pdm1[j] = pd;
    }
  }

  if (CHEAD == 64){
    const int hy = blockIdx.y*2 + wc;
    if ((l & 15) == 0){
      const int rb0 = m0 + wr*32 + (l >> 4)*4;
      #pragma unroll
      for (int j = 0; j < 4; ++j){
        int row = rb0 + j;
        if (row < M){ as4[(size_t)row*4 + hy] = psm0[j]; ad4[(size_t)row*4 + hy] = pdm0[j]; }
      }
      const int rb1 = rb0 + 16;
      #pragma unroll
      for (int j = 0; j < 4; ++j){
        int row = rb1 + j;
        if (row < M){ as4[(size_t)row*4 + hy] = psm1[j]; ad4[(size_t)row*4 + hy] = pdm1[j]; }
      }
    }
  } else {
    float* red = (float*)&sA[0][0];    // 1 KB
    __syncthreads();
    if ((l & 15) == 0){
      const int lr0 = wr*32 + (l >> 4)*4;
      #pragma unroll
      for (int j = 0; j < 4; ++j){
        red[(lr0 + j)*4 + wc*2 + 0] = psm0[j];
        red[(lr0 + j)*4 + wc*2 + 1] = pdm0[j];
      }
      const int lr1 = lr0 + 16;
      #pragma unroll
      for (int j = 0; j < 4; ++j){
        red[(lr1 + j)*4 + wc*2 + 0] = psm1[j];
        red[(lr1 + j)*4 + wc*2 + 1] = pdm1[j];
      }
    }
    __syncthreads();
    if (tid < 64){
      int row = m0 + tid;
      if (row < M){
        float ps = red[tid*4 + 0] + red[tid*4 + 2];
        float pd = red[tid*4 + 1] + red[tid*4 + 3];
        as4[(size_t)row*4 + blockIdx.y] = ps;
        ad4[(size_t)row*4 + blockIdx.y] = pd;
      }
    }
  }
}

// ---------------- fp16-gather agg: shuffle-free phase B via precomputed edge alpha ----------------
// Phase A: per-node softmax stats (lane-strided, butterfly reduce).
// Weight pass: same wave writes alpha (float4 per edge) to awt — bit-identical math.
// Phase B: per edge j (uniform): sidx = es[j] (scalar load), u = awt[j*4+myh] (L1) — ZERO DS ops.
template<int HC>
__global__ __launch_bounds__(256)
void k_agg_h(const int* __restrict__ rp, const int* __restrict__ es,
             const float* __restrict__ as4, const float* __restrict__ ad4,
             const _Float16* __restrict__ h, const float* __restrict__ bias,
             float* __restrict__ awt, _Float16* __restrict__ oH, int N){
  constexpr int VEC = HC / 64;           // halves per lane (4 or 8)
  int wid  = (blockIdx.x*blockDim.x + threadIdx.x) >> 6;
  int lane = threadIdx.x & 63;
  if (wid >= N) return;
  int beg = rp[wid], end = rp[wid+1];

  const float4 adv = *(const float4*)(ad4 + (size_t)wid*4);
  const float ad0 = adv.x, ad1 = adv.y, ad2 = adv.z, ad3 = adv.w;

  // phase A: online softmax stats per head
  float m0=-1e30f, m1=-1e30f, m2=-1e30f, m3=-1e30f;
  float s0=0.f, s1=0.f, s2=0.f, s3=0.f;
  for (int i = beg + lane; i < end; i += WAVE){
    int s = es[i];
    const float4 av = *(const float4*)(as4 + (size_t)s*4);
    float e, mn;
    e = av.x + ad0; e = (e >= 0.f) ? e : 0.2f*e;
    mn = fmaxf(m0, e); s0 = s0*__expf(m0-mn) + __expf(e-mn); m0 = mn;
    e = av.y + ad1; e = (e >= 0.f) ? e : 0.2f*e;
    mn = fmaxf(m1, e); s1 = s1*__expf(m1-mn) + __expf(e-mn); m1 = mn;
    e = av.z + ad2; e = (e >= 0.f) ? e : 0.2f*e;
    mn = fmaxf(m2, e); s2 = s2*__expf(m2-mn) + __expf(e-mn); m2 = mn;
    e = av.w + ad3; e = (e >= 0.f) ? e : 0.2f*e;
    mn = fmaxf(m3, e); s3 = s3*__expf(m3-mn) + __expf(e-mn); m3 = mn;
  }
  #pragma unroll
  for (int off = 32; off > 0; off >>= 1){
    float mo, so, mn;
    mo = __shfl_xor(m0, off, WAVE); so = __shfl_xor(s0, off, WAVE);
    mn = fmaxf(m0, mo); s0 = s0*__expf(m0-mn) + so*__expf(mo-mn); m0 = mn;
    mo = __shfl_xor(m1, off, WAVE); so = __shfl_xor(s1, off, WAVE);
    mn = fmaxf(m1, mo); s1 = s1*__expf(m1-mn) + so*__expf(mo-mn); m1 = mn;
    mo = __shfl_xor(m2, off, WAVE); so = __shfl_xor(s2, off, WAVE);
    mn = fmaxf(m2, mo); s2 = s2*__expf(m2-mn) + so*__expf(mo-mn); m2 = mn;
    mo = __shfl_xor(m3, off, WAVE); so = __shfl_xor(s3, off, WAVE);
    mn = fmaxf(m3, mo); s3 = s3*__expf(m3-mn) + so*__expf(mo-mn); m3 = mn;
  }
  const float i0 = 1.f/(s0 + 1e-16f), i1 = 1.f/(s1 + 1e-16f);
  const float i2 = 1.f/(s2 + 1e-16f), i3 = 1.f/(s3 + 1e-16f);

  // weight pass: write per-edge alpha (float4) — same math as before, once per edge
  for (int i = beg + lane; i < end; i += WAVE){
    int s = es[i];
    const float4 av = *(const float4*)(as4 + (size_t)s*4);
    float e;
    float4 wv;
    e = av.x + ad0; e = (e >= 0.f) ? e : 0.2f*e; wv.x = __expf(e - m0)*i0;
    e = av.y + ad1; e = (e >= 0.f) ? e : 0.2f*e; wv.y = __expf(e - m1)*i1;
    e = av.z + ad2; e = (e >= 0.f) ? e : 0.2f*e; wv.z = __expf(e - m2)*i2;
    e = av.w + ad3; e = (e >= 0.f) ? e : 0.2f*e; wv.w = __expf(e - m3)*i3;
    *(float4*)(awt + (size_t)i*4) = wv;
  }
  // ensure this wave's alpha stores are visible to its own (cross-lane) loads below
  asm volatile("s_waitcnt vmcnt(0)" ::: "memory");

  const int myh = lane >> 4;           // head for this lane's columns (both VEC cases)
  float ac[VEC] = {};

  // phase B: shuffle-free weighted gather
  int j = beg;
  for (; j + 4 <= end; j += 4){
    int sj0 = es[j], sj1 = es[j+1], sj2 = es[j+2], sj3 = es[j+3];
    float u0 = awt[(size_t)j*4 + myh];
    float u1 = awt[(size_t)(j+1)*4 + myh];
    float u2 = awt[(size_t)(j+2)*4 + myh];
    float u3 = awt[(size_t)(j+3)*4 + myh];
    if (VEC == 4){
      h16x4 v0 = *(const h16x4*)(h + (size_t)sj0*HC + lane*4);
      h16x4 v1 = *(const h16x4*)(h + (size_t)sj1*HC + lane*4);
      h16x4 v2 = *(const h16x4*)(h + (size_t)sj2*HC + lane*4);
      h16x4 v3 = *(const h16x4*)(h + (size_t)sj3*HC + lane*4);
      #pragma unroll
      for (int c = 0; c < 4; ++c)
        ac[c] = fmaf(u0,(float)v0[c], fmaf(u1,(float)v1[c], fmaf(u2,(float)v2[c], fmaf(u3,(float)v3[c], ac[c]))));
    } else {
      h16x8 v0 = *(const h16x8*)(h + (size_t)sj0*HC + lane*8);
      h16x8 v1 = *(const h16x8*)(h + (size_t)sj1*HC + lane*8);
      h16x8 v2 = *(const h16x8*)(h + (size_t)sj2*HC + lane*8);
      h16x8 v3 = *(const h16x8*)(h + (size_t)sj3*HC + lane*8);
      #pragma unroll
      for (int c = 0; c < VEC; ++c)
        ac[c] = fmaf(u0,(float)v0[c], fmaf(u1,(float)v1[c], fmaf(u2,(float)v2[c], fmaf(u3,(float)v3[c], ac[c]))));
    }
  }
  for (; j < end; ++j){
    int sj = es[j];
    float u = awt[(size_t)j*4 + myh];
    if (VEC == 4){
      h16x4 v = *(const h16x4*)(h + (size_t)sj*HC + lane*4);
      #pragma unroll
      for (int c = 0; c < 4; ++c) ac[c] = fmaf(u, (float)v[c], ac[c]);
    } else {
      h16x8 v = *(const h16x8*)(h + (size_t)sj*HC + lane*8);
      #pragma unroll
      for (int c = 0; c < VEC; ++c) ac[c] = fmaf(u, (float)v[c], ac[c]);
    }
  }

  float r0=0,r1=0,r2=0,r3=0,r4=0,r5=0,r6=0,r7=0;
  {
    const float* bp = bias + lane*VEC;
    #pragma unroll
    for (int c = 0; c < VEC; ++c){
      float r = ac[c] + bp[c];
      r = r > 0.f ? r : expm1f(r);
      if (c==0) r0=r; else if (c==1) r1=r; else if (c==2) r2=r; else if (c==3) r3=r;
      else if (c==4) r4=r; else if (c==5) r5=r; else if (c==6) r6=r; else r7=r;
    }
  }
  h16x4 o;
  o[0] = (_Float16)r0; o[1] = (_Float16)r1;
  o[2] = (_Float16)r2; o[3] = (_Float16)r3;
  *(h16x4*)(oH + (size_t)wid*HC + lane*VEC) = o;
  if (VEC == 8){
    h16x4 o2;
    o2[0] = (_Float16)r4; o2[1] = (_Float16)r5;
    o2[2] = (_Float16)r6; o2[3] = (_Float16)r7;
    *(h16x4*)(oH + (size_t)wid*HC + lane*VEC + 4) = o2;
  }
}

// ---------------- pooling (fp16 input) + fused final/FC ----------------
__global__ void k_pool_partial(const _Float16* __restrict__ h, const int* __restrict__ bs,
                               float* __restrict__ psum, float* __restrict__ pmax){
  int b = blockIdx.x, ch = blockIdx.y;
  int f = threadIdx.x;
  int s = bs[b], e = bs[b+1];
  long long len = e - s;
  int i0 = s + (int)(len * ch / 8);
  int i1 = s + (int)(len * (ch+1) / 8);
  float sm = 0.f, mx = -3.0e38f;
  for (int i = i0; i < i1; ++i){
    float v = (float)h[(size_t)i*512 + f];
    sm += v; mx = fmaxf(mx, v);
  }
  int idx = (b*8 + ch)*512 + f;
  psum[idx] = sm; pmax[idx] = mx;
}

__global__ __launch_bounds__(256)
void k_fc(const float* __restrict__ psum, const float* __restrict__ pmax,
          const int* __restrict__ bs, const float* __restrict__ fcW,
          const float* __restrict__ fcb, float* __restrict__ out){
  __shared__ float gs[1024];
  __shared__ float red[4][64];
  int b = blockIdx.x, t = threadIdx.x;
  int o0 = blockIdx.y * 64;
  int cntb = bs[b+1] - bs[b];
  float inv = 1.f / fmaxf((float)cntb, 1.f);
  for (int i = t; i < 512; i += 256){
    float sm = 0.f, mx = -3.0e38f;
    #pragma unroll
    for (int c = 0; c < 8; ++c){
      int idx = (b*8 + c)*512 + i;
      sm += psum[idx]; mx = fmaxf(mx, pmax[idx]);
    }
    gs[i] = sm * inv;
    gs[512 + i] = (mx > -1e37f) ? mx : 0.f;
  }
  __syncthreads();
  int ol = t & 63, q = t >> 6;
  const float* wp = fcW + (size_t)(q*256)*512 + o0 + ol;
  float acc = 0.f;
  #pragma unroll 8
  for (int k = 0; k < 256; ++k)
    acc = fmaf(gs[q*256 + k], wp[(size_t)k*512], acc);
  red[q][ol] = acc;
  __syncthreads();
  if (t < 64){
    float r = red[0][t] + red[1][t] + red[2][t] + red[3][t] + fcb[o0 + t];
    out[b*512 + o0 + t] = r;
  }
}

// ---------------- launcher ----------------
extern "C" void kernel_launch(void* const* d_in, const int* in_sizes, int n_in,
                              void* d_out, int out_size, void* d_ws, size_t ws_size,
                              hipStream_t stream){
  (void)n_in; (void)out_size; (void)ws_size;
  const float* x     = (const float*)d_in[0];
  const int*   ei    = (const int*)d_in[1];
  const int*   batch = (const int*)d_in[2];
  const float* W[4]   = {(const float*)d_in[3],(const float*)d_in[7],(const float*)d_in[11],(const float*)d_in[15]};
  const float* asr[4] = {(const float*)d_in[4],(const float*)d_in[8],(const float*)d_in[12],(const float*)d_in[16]};
  const float* adt[4] = {(const float*)d_in[5],(const float*)d_in[9],(const float*)d_in[13],(const float*)d_in[17]};
  const float* bb[4]  = {(const float*)d_in[6],(const float*)d_in[10],(const float*)d_in[14],(const float*)d_in[18]};
  const float* fcW = (const float*)d_in[19];
  const float* fcb = (const float*)d_in[20];

  const int N  = in_sizes[0] / 128;
  const int E  = in_sizes[1] / 2;
  const int EN = E + N;
  const int B  = 32;
  const int NB = (N + 1023) / 1024;

  char* p = (char*)d_ws;
  auto alloc = [&](size_t bytes){ void* r = (void*)p; p += (bytes + 255) & ~(size_t)255; return r; };
  _Float16* hA = (_Float16*)alloc((size_t)N*512*2);        // GEMM out (gather input)
  _Float16* hB = (_Float16*)alloc((size_t)N*512*2);        // agg out (next GEMM A / pool input)
  _Float16* Wh = (_Float16*)alloc((size_t)294912*2);       // all W^T f16, packed
  float* awt  = (float*)alloc((size_t)EN*4*4);             // per-edge alpha (4 heads)
  float* a2   = (float*)alloc((size_t)N*8*4);              // as4 | ad4
  float* as4 = a2;
  float* ad4 = a2 + (size_t)N*4;
  int*   cntdone = (int*)alloc((size_t)(N+64)*4);          // cnt[N] + done[1]
  int*   cnt  = cntdone;
  int*   done = cntdone + N;
  int*   rp   = (int*)alloc((size_t)(N+1)*4);
  int*   cur  = (int*)alloc((size_t)N*4);
  int*   es   = (int*)alloc((size_t)EN*4);
  int*   bs   = (int*)alloc((size_t)(B+1)*4);
  int*   bsum = (int*)alloc((size_t)64*4);
  float* psum = (float*)alloc((size_t)B*8*512*4);
  float* pmax = (float*)alloc((size_t)B*8*512*4);

  hipMemsetAsync(cntdone, 0, (size_t)(N+1)*4, stream);

  const int CB = (EN + 255)/256;
  const int XB = (N*32 + 255)/256;
  const int WB = (294912 + 255)/256;
  k_front<<<CB + XB + WB + 1, 256, 0, stream>>>(ei, E, N, cnt, x, hB,
                                                W[0], W[1], W[2], W[3], Wh,
                                                batch, B, bs, CB, XB, WB);

  k_scan1<<<NB, 1024, 0, stream>>>(cnt, rp, bsum, done, N, NB);
  k_scan3<<<NB, 1024, 0, stream>>>(rp, cur, bsum, N);
  k_fill<<<(EN+255)/256, 256, 0, stream>>>(ei, E, N, cur, es);

  const int wgrid = (N + 3) / 4;
  const int Kd[4]  = {128, 256, 256, 256};
  const int HCd[4] = {256, 256, 256, 512};
  const size_t Woff[4] = {0, 32768, 98304, 163840};

  for (int L = 0; L < 4; ++L){
    const int K = Kd[L], Nc = HCd[L];
    dim3 gg((N + 63)/64, Nc/128);
    if (Nc == 256)
      k_gemm_fused<64><<<gg, 256, 0, stream>>>(hB, Wh + Woff[L], hA, asr[L], adt[L], as4, ad4, N, K, Nc);
    else
      k_gemm_fused<128><<<gg, 256, 0, stream>>>(hB, Wh + Woff[L], hA, asr[L], adt[L], as4, ad4, N, K, Nc);
    if (Nc == 256)
      k_agg_h<256><<<wgrid, 256, 0, stream>>>(rp, es, as4, ad4, hA, bb[L], awt, hB, N);
    else
      k_agg_h<512><<<wgrid, 256, 0, stream>>>(rp, es, as4, ad4, hA, bb[L], awt, hB, N);
  }

  dim3 pg(B, 8);
  k_pool_partial<<<pg, 512, 0, stream>>>(hB, bs, psum, pmax);
  dim3 fg(B, 8);
  k_fc<<<fg, 256, 0, stream>>>(psum, pmax, bs, fcW, fcb, (float*)d_out);
}

// Round 12
// 440.866 us; speedup vs baseline: 1.0404x; 1.0404x over previous
//
#include <hip/hip_runtime.h>
#include <math.h>

#define WAVE 64

typedef __attribute__((ext_vector_type(4))) float f32x4;
typedef _Float16 h16x4 __attribute__((ext_vector_type(4)));
typedef _Float16 h16x8 __attribute__((ext_vector_type(8)));

__device__ __forceinline__ float selh(float e0, float e1, float e2, float e3, int m){
  float r = (m == 1) ? e1 : e0;
  r = (m == 2) ? e2 : r;
  r = (m == 3) ? e3 : r;
  return r;
}

// ---------------- fused front: count | cvt16 | cvt_w_all | bounds ----------------
__global__ __launch_bounds__(256)
void k_front(const int* __restrict__ ei, int E, int N, int* __restrict__ cnt,
             const float* __restrict__ x, _Float16* __restrict__ hB,
             const float* __restrict__ W0, const float* __restrict__ W1,
             const float* __restrict__ W2, const float* __restrict__ W3,
             _Float16* __restrict__ Wh,
             const int* __restrict__ batch, int B, int* __restrict__ bs,
             int CB, int XB, int WB){
  int bid = blockIdx.x, t = threadIdx.x;
  if (bid < CB){
    int i = bid*256 + t;
    if (i < E + N){
      int d = (i < E) ? ei[E + i] : (i - E);
      atomicAdd(&cnt[d], 1);
    }
  } else if (bid < CB + XB){
    int i = (bid - CB)*256 + t;
    if (i < N*32){
      float4 v = ((const float4*)x)[i];
      h16x4 o;
      o[0] = (_Float16)v.x; o[1] = (_Float16)v.y;
      o[2] = (_Float16)v.z; o[3] = (_Float16)v.w;
      ((h16x4*)hB)[i] = o;
    }
  } else if (bid < CB + XB + WB){
    int i = (bid - CB - XB)*256 + t;
    if (i < 32768){                       // L1: K=128, Nc=256
      int k = i >> 8, n = i & 255;
      Wh[(size_t)n*128 + k] = (_Float16)W0[i];
    } else if (i < 98304){                // L2
      int j = i - 32768; int k = j >> 8, n = j & 255;
      Wh[32768 + (size_t)n*256 + k] = (_Float16)W1[j];
    } else if (i < 163840){               // L3
      int j = i - 98304; int k = j >> 8, n = j & 255;
      Wh[98304 + (size_t)n*256 + k] = (_Float16)W2[j];
    } else if (i < 294912){               // L4: K=256, Nc=512
      int j = i - 163840; int k = j >> 9, n = j & 511;
      Wh[163840 + (size_t)n*256 + k] = (_Float16)W3[j];
    }
  } else {
    int b = t;
    if (b <= B){
      int lo = 0, hi = N;
      while (lo < hi){ int mid = (lo + hi) >> 1; if (batch[mid] < b) lo = mid + 1; else hi = mid; }
      bs[b] = lo;
    }
  }
}

// ---------------- scan1 with fused block-sum scan (last-block pattern) ----------------
__global__ __launch_bounds__(1024)
void k_scan1(const int* __restrict__ cnt, int* __restrict__ rp, int* __restrict__ bsum,
             int* __restrict__ done, int N, int nb){
  __shared__ int sd[1024];
  int t = threadIdx.x, i = blockIdx.x*1024 + t;
  int v = (i < N) ? cnt[i] : 0;
  sd[t] = v;
  __syncthreads();
  for (int off = 1; off < 1024; off <<= 1){
    int x = (t >= off) ? sd[t-off] : 0;
    __syncthreads();
    sd[t] += x;
    __syncthreads();
  }
  if (i < N) rp[i] = sd[t] - v;
  if (t == 1023) bsum[blockIdx.x] = sd[1023];
  __threadfence();
  __syncthreads();
  if (t == 0){
    if (atomicAdd(done, 1) == nb - 1){
      int run = 0;
      for (int b2 = 0; b2 < nb; ++b2){ int s = bsum[b2]; bsum[b2] = run; run += s; }
      rp[N] = run;
    }
  }
}

__global__ __launch_bounds__(1024)
void k_scan3(int* __restrict__ rp, int* __restrict__ cur, const int* __restrict__ bsum, int N){
  int i = blockIdx.x*1024 + threadIdx.x;
  if (i < N){
    int v = rp[i] + bsum[blockIdx.x];
    rp[i] = v;
    cur[i] = v;
  }
}

__global__ void k_fill(const int* __restrict__ ei, int E, int N,
                       int* __restrict__ cur, int* __restrict__ es){
  int i = blockIdx.x*blockDim.x + threadIdx.x;
  if (i >= E + N) return;
  int s, d;
  if (i < E){ s = ei[i]; d = ei[E + i]; } else { s = d = i - E; }
  int pos = atomicAdd(&cur[d], 1);
  es[pos] = s;
}

// ---------------- fp16 MFMA GEMM (64x128 tile, 4 waves, dbuf LDS), fused alpha ----------------
template<int CHEAD>
__global__ __launch_bounds__(256)
void k_gemm_fused(const _Float16* __restrict__ Ax, const _Float16* __restrict__ Bw,
                  _Float16* __restrict__ Ch,
                  const float* __restrict__ asr, const float* __restrict__ adt,
                  float* __restrict__ as4, float* __restrict__ ad4,
                  int M, int K, int Nc){
  constexpr int LDP = 40;
  __shared__ _Float16 sA[2][64*LDP], sB[2][128*LDP];   // 10 KB + 20.5 KB
  const int tid = threadIdx.x;
  const int m0 = blockIdx.x*64, n0 = blockIdx.y*128;
  const int w = tid >> 6, l = tid & 63;
  const int wr = w >> 1, wc = w & 1;          // 2M x 2N waves
  const int sr = tid >> 2, sc = (tid & 3)*8;  // 64 rows x 4 thr/row x 8 halves

  f32x4 acc00={0.f,0.f,0.f,0.f}, acc01=acc00, acc02=acc00, acc03=acc00;
  f32x4 acc10=acc00, acc11=acc00, acc12=acc00, acc13=acc00;

  const int arow = m0 + sr;
  const bool aval = arow < M;
  const size_t aoff  = (size_t)arow*K + sc;
  const size_t boff0 = (size_t)(n0 + sr)*K + sc;
  const size_t boff1 = (size_t)(n0 + 64 + sr)*K + sc;

  const int fa0 = (wr*32 + (l & 15))*LDP + (l >> 4)*8;
  const int fa1 = fa0 + 16*LDP;
  const int fb0 = (wc*64 + (l & 15))*LDP + (l >> 4)*8;
  const int steps = K >> 5;

  uint4 va = make_uint4(0,0,0,0), vb0, vb1;
  if (aval) va = *(const uint4*)(Ax + aoff);
  vb0 = *(const uint4*)(Bw + boff0);
  vb1 = *(const uint4*)(Bw + boff1);
  *(uint4*)&sA[0][sr*LDP + sc] = va;
  *(uint4*)&sB[0][sr*LDP + sc] = vb0;
  *(uint4*)&sB[0][(64 + sr)*LDP + sc] = vb1;
  __syncthreads();

  for (int ks = 0; ks < steps; ++ks){
    const int cur = ks & 1;
    const bool more = (ks + 1 < steps);
    if (more){
      const int k0 = (ks + 1)*32;
      va = make_uint4(0,0,0,0);
      if (aval) va = *(const uint4*)(Ax + aoff + k0);
      vb0 = *(const uint4*)(Bw + boff0 + k0);
      vb1 = *(const uint4*)(Bw + boff1 + k0);
    }

    h16x8 a0 = *(const h16x8*)&sA[cur][fa0];
    h16x8 a1 = *(const h16x8*)&sA[cur][fa1];
    h16x8 b;
    b = *(const h16x8*)&sB[cur][fb0];
    acc00 = __builtin_amdgcn_mfma_f32_16x16x32_f16(a0, b, acc00, 0, 0, 0);
    acc10 = __builtin_amdgcn_mfma_f32_16x16x32_f16(a1, b, acc10, 0, 0, 0);
    b = *(const h16x8*)&sB[cur][fb0 + 16*LDP];
    acc01 = __builtin_amdgcn_mfma_f32_16x16x32_f16(a0, b, acc01, 0, 0, 0);
    acc11 = __builtin_amdgcn_mfma_f32_16x16x32_f16(a1, b, acc11, 0, 0, 0);
    b = *(const h16x8*)&sB[cur][fb0 + 32*LDP];
    acc02 = __builtin_amdgcn_mfma_f32_16x16x32_f16(a0, b, acc02, 0, 0, 0);
    acc12 = __builtin_amdgcn_mfma_f32_16x16x32_f16(a1, b, acc12, 0, 0, 0);
    b = *(const h16x8*)&sB[cur][fb0 + 48*LDP];
    acc03 = __builtin_amdgcn_mfma_f32_16x16x32_f16(a0, b, acc03, 0, 0, 0);
    acc13 = __builtin_amdgcn_mfma_f32_16x16x32_f16(a1, b, acc13, 0, 0, 0);

    if (more){
      *(uint4*)&sA[cur^1][sr*LDP + sc] = va;
      *(uint4*)&sB[cur^1][sr*LDP + sc] = vb0;
      *(uint4*)&sB[cur^1][(64 + sr)*LDP + sc] = vb1;
      __syncthreads();
    }
  }

  // C/D layout per 16x16 frag: col = lane&15, row = (lane>>4)*4 + j
  const int colb = n0 + wc*64 + (l & 15);
  const float ca0 = asr[colb], ca1 = asr[colb+16], ca2 = asr[colb+32], ca3 = asr[colb+48];
  const float cd0 = adt[colb], cd1 = adt[colb+16], cd2 = adt[colb+32], cd3 = adt[colb+48];

  float psm0[4], pdm0[4], psm1[4], pdm1[4];   // compile-time unrolled only
  {
    const int rb = m0 + wr*32 + (l >> 4)*4;
    #pragma unroll
    for (int j = 0; j < 4; ++j){
      int row = rb + j;
      if (row < M){
        _Float16* hp = Ch + (size_t)row*Nc + colb;
        hp[0]  = (_Float16)acc00[j];
        hp[16] = (_Float16)acc01[j];
        hp[32] = (_Float16)acc02[j];
        hp[48] = (_Float16)acc03[j];
      }
      float ps = ca0*acc00[j] + ca1*acc01[j] + ca2*acc02[j] + ca3*acc03[j];
      float pd = cd0*acc00[j] + cd1*acc01[j] + cd2*acc02[j] + cd3*acc03[j];
      ps += __shfl_xor(ps, 1, WAVE);  pd += __shfl_xor(pd, 1, WAVE);
      ps += __shfl_xor(ps, 2, WAVE);  pd += __shfl_xor(pd, 2, WAVE);
      ps += __shfl_xor(ps, 4, WAVE);  pd += __shfl_xor(pd, 4, WAVE);
      ps += __shfl_xor(ps, 8, WAVE);  pd += __shfl_xor(pd, 8, WAVE);
      psm0[j] = ps; pdm0[j] = pd;
    }
  }
  {
    const int rb = m0 + wr*32 + 16 + (l >> 4)*4;
    #pragma unroll
    for (int j = 0; j < 4; ++j){
      int row = rb + j;
      if (row < M){
        _Float16* hp = Ch + (size_t)row*Nc + colb;
        hp[0]  = (_Float16)acc10[j];
        hp[16] = (_Float16)acc11[j];
        hp[32] = (_Float16)acc12[j];
        hp[48] = (_Float16)acc13[j];
      }
      float ps = ca0*acc10[j] + ca1*acc11[j] + ca2*acc12[j] + ca3*acc13[j];
      float pd = cd0*acc10[j] + cd1*acc11[j] + cd2*acc12[j] + cd3*acc13[j];
      ps += __shfl_xor(ps, 1, WAVE);  pd += __shfl_xor(pd, 1, WAVE);
      ps += __shfl_xor(ps, 2, WAVE);  pd += __shfl_xor(pd, 2, WAVE);
      ps += __shfl_xor(ps, 4, WAVE);  pd += __shfl_xor(pd, 4, WAVE);
      ps += __shfl_xor(ps, 8, WAVE);  pd += __shfl_xor(pd, 8, WAVE);
      psm1[j] = ps; pdm1[j] = pd;
    }
  }

  if (CHEAD == 64){
    const int hy = blockIdx.y*2 + wc;
    if ((l & 15) == 0){
      const int rb0 = m0 + wr*32 + (l >> 4)*4;
      #pragma unroll
      for (int j = 0; j < 4; ++j){
        int row = rb0 + j;
        if (row < M){ as4[(size_t)row*4 + hy] = psm0[j]; ad4[(size_t)row*4 + hy] = pdm0[j]; }
      }
      const int rb1 = rb0 + 16;
      #pragma unroll
      for (int j = 0; j < 4; ++j){
        int row = rb1 + j;
        if (row < M){ as4[(size_t)row*4 + hy] = psm1[j]; ad4[(size_t)row*4 + hy] = pdm1[j]; }
      }
    }
  } else {
    float* red = (float*)&sA[0][0];    // 1 KB
    __syncthreads();
    if ((l & 15) == 0){
      const int lr0 = wr*32 + (l >> 4)*4;
      #pragma unroll
      for (int j = 0; j < 4; ++j){
        red[(lr0 + j)*4 + wc*2 + 0] = psm0[j];
        red[(lr0 + j)*4 + wc*2 + 1] = pdm0[j];
      }
      const int lr1 = lr0 + 16;
      #pragma unroll
      for (int j = 0; j < 4; ++j){
        red[(lr1 + j)*4 + wc*2 + 0] = psm1[j];
        red[(lr1 + j)*4 + wc*2 + 1] = pdm1[j];
      }
    }
    __syncthreads();
    if (tid < 64){
      int row = m0 + tid;
      if (row < M){
        float ps = red[tid*4 + 0] + red[tid*4 + 2];
        float pd = red[tid*4 + 1] + red[tid*4 + 3];
        as4[(size_t)row*4 + blockIdx.y] = ps;
        ad4[(size_t)row*4 + blockIdx.y] = pd;
      }
    }
  }
}

// ---------------- fp16-gather agg (all layers; fp16 out) ----------------
template<int HC>
__global__ __launch_bounds__(256)
void k_agg_h(const int* __restrict__ rp, const int* __restrict__ es,
             const float* __restrict__ as4, const float* __restrict__ ad4,
             const _Float16* __restrict__ h, const float* __restrict__ bias,
             _Float16* __restrict__ oH, int N){
  constexpr int VEC = HC / 64;           // halves per lane (4 or 8)
  int wid  = (blockIdx.x*blockDim.x + threadIdx.x) >> 6;
  int lane = threadIdx.x & 63;
  if (wid >= N) return;
  int beg = rp[wid], end = rp[wid+1];

  const float4 adv = *(const float4*)(ad4 + (size_t)wid*4);
  const float ad0 = adv.x, ad1 = adv.y, ad2 = adv.z, ad3 = adv.w;

  float m0=-1e30f, m1=-1e30f, m2=-1e30f, m3=-1e30f;
  float s0=0.f, s1=0.f, s2=0.f, s3=0.f;
  for (int i = beg + lane; i < end; i += WAVE){
    int s = es[i];
    const float4 av = *(const float4*)(as4 + (size_t)s*4);
    float e, mn;
    e = av.x + ad0; e = (e >= 0.f) ? e : 0.2f*e;
    mn = fmaxf(m0, e); s0 = s0*__expf(m0-mn) + __expf(e-mn); m0 = mn;
    e = av.y + ad1; e = (e >= 0.f) ? e : 0.2f*e;
    mn = fmaxf(m1, e); s1 = s1*__expf(m1-mn) + __expf(e-mn); m1 = mn;
    e = av.z + ad2; e = (e >= 0.f) ? e : 0.2f*e;
    mn = fmaxf(m2, e); s2 = s2*__expf(m2-mn) + __expf(e-mn); m2 = mn;
    e = av.w + ad3; e = (e >= 0.f) ? e : 0.2f*e;
    mn = fmaxf(m3, e); s3 = s3*__expf(m3-mn) + __expf(e-mn); m3 = mn;
  }
  #pragma unroll
  for (int off = 32; off > 0; off >>= 1){
    float mo, so, mn;
    mo = __shfl_xor(m0, off, WAVE); so = __shfl_xor(s0, off, WAVE);
    mn = fmaxf(m0, mo); s0 = s0*__expf(m0-mn) + so*__expf(mo-mn); m0 = mn;
    mo = __shfl_xor(m1, off, WAVE); so = __shfl_xor(s1, off, WAVE);
    mn = fmaxf(m1, mo); s1 = s1*__expf(m1-mn) + so*__expf(mo-mn); m1 = mn;
    mo = __shfl_xor(m2, off, WAVE); so = __shfl_xor(s2, off, WAVE);
    mn = fmaxf(m2, mo); s2 = s2*__expf(m2-mn) + so*__expf(mo-mn); m2 = mn;
    mo = __shfl_xor(m3, off, WAVE); so = __shfl_xor(s3, off, WAVE);
    mn = fmaxf(m3, mo); s3 = s3*__expf(m3-mn) + so*__expf(mo-mn); m3 = mn;
  }
  const float i0 = 1.f/(s0 + 1e-16f), i1 = 1.f/(s1 + 1e-16f);
  const float i2 = 1.f/(s2 + 1e-16f), i3 = 1.f/(s3 + 1e-16f);
  const int myh = lane >> 4;

  float ac[VEC] = {};

  for (int cb = beg; cb < end; cb += WAVE){
    int nn = min(WAVE, end - cb);
    int sidx = 0;
    float w0 = 0.f, w1 = 0.f, w2 = 0.f, w3 = 0.f;
    if (cb + lane < end){
      sidx = es[cb + lane];
      const float4 av = *(const float4*)(as4 + (size_t)sidx*4);
      float e;
      e = av.x + ad0; e = (e >= 0.f) ? e : 0.2f*e; w0 = __expf(e - m0)*i0;
      e = av.y + ad1; e = (e >= 0.f) ? e : 0.2f*e; w1 = __expf(e - m1)*i1;
      e = av.z + ad2; e = (e >= 0.f) ? e : 0.2f*e; w2 = __expf(e - m2)*i2;
      e = av.w + ad3; e = (e >= 0.f) ? e : 0.2f*e; w3 = __expf(e - m3)*i3;
    }

    int j = 0;
    for (; j + 4 <= nn; j += 4){
      int sj0 = __shfl(sidx, j+0, WAVE), sj1 = __shfl(sidx, j+1, WAVE);
      int sj2 = __shfl(sidx, j+2, WAVE), sj3 = __shfl(sidx, j+3, WAVE);
      float u0 = selh(__shfl(w0,j+0,WAVE), __shfl(w1,j+0,WAVE), __shfl(w2,j+0,WAVE), __shfl(w3,j+0,WAVE), myh);
      float u1 = selh(__shfl(w0,j+1,WAVE), __shfl(w1,j+1,WAVE), __shfl(w2,j+1,WAVE), __shfl(w3,j+1,WAVE), myh);
      float u2 = selh(__shfl(w0,j+2,WAVE), __shfl(w1,j+2,WAVE), __shfl(w2,j+2,WAVE), __shfl(w3,j+2,WAVE), myh);
      float u3 = selh(__shfl(w0,j+3,WAVE), __shfl(w1,j+3,WAVE), __shfl(w2,j+3,WAVE), __shfl(w3,j+3,WAVE), myh);
      if (VEC == 4){
        h16x4 v0 = *(const h16x4*)(h + (size_t)sj0*HC + lane*4);
        h16x4 v1 = *(const h16x4*)(h + (size_t)sj1*HC + lane*4);
        h16x4 v2 = *(const h16x4*)(h + (size_t)sj2*HC + lane*4);
        h16x4 v3 = *(const h16x4*)(h + (size_t)sj3*HC + lane*4);
        #pragma unroll
        for (int c = 0; c < 4; ++c)
          ac[c] = fmaf(u0,(float)v0[c], fmaf(u1,(float)v1[c], fmaf(u2,(float)v2[c], fmaf(u3,(float)v3[c], ac[c]))));
      } else {
        h16x8 v0 = *(const h16x8*)(h + (size_t)sj0*HC + lane*8);
        h16x8 v1 = *(const h16x8*)(h + (size_t)sj1*HC + lane*8);
        h16x8 v2 = *(const h16x8*)(h + (size_t)sj2*HC + lane*8);
        h16x8 v3 = *(const h16x8*)(h + (size_t)sj3*HC + lane*8);
        #pragma unroll
        for (int c = 0; c < VEC; ++c)
          ac[c] = fmaf(u0,(float)v0[c], fmaf(u1,(float)v1[c], fmaf(u2,(float)v2[c], fmaf(u3,(float)v3[c], ac[c]))));
      }
    }
    for (; j < nn; ++j){
      int sj = __shfl(sidx, j, WAVE);
      float u = selh(__shfl(w0,j,WAVE), __shfl(w1,j,WAVE), __shfl(w2,j,WAVE), __shfl(w3,j,WAVE), myh);
      if (VEC == 4){
        h16x4 v = *(const h16x4*)(h + (size_t)sj*HC + lane*4);
        #pragma unroll
        for (int c = 0; c < 4; ++c) ac[c] = fmaf(u, (float)v[c], ac[c]);
      } else {
        h16x8 v = *(const h16x8*)(h + (size_t)sj*HC + lane*8);
        #pragma unroll
        for (int c = 0; c < VEC; ++c) ac[c] = fmaf(u, (float)v[c], ac[c]);
      }
    }
  }

  float r0=0,r1=0,r2=0,r3=0,r4=0,r5=0,r6=0,r7=0;
  {
    const float* bp = bias + lane*VEC;
    #pragma unroll
    for (int c = 0; c < VEC; ++c){
      float r = ac[c] + bp[c];
      r = r > 0.f ? r : expm1f(r);
      if (c==0) r0=r; else if (c==1) r1=r; else if (c==2) r2=r; else if (c==3) r3=r;
      else if (c==4) r4=r; else if (c==5) r5=r; else if (c==6) r6=r; else r7=r;
    }
  }
  h16x4 o;
  o[0] = (_Float16)r0; o[1] = (_Float16)r1;
  o[2] = (_Float16)r2; o[3] = (_Float16)r3;
  *(h16x4*)(oH + (size_t)wid*HC + lane*VEC) = o;
  if (VEC == 8){
    h16x4 o2;
    o2[0] = (_Float16)r4; o2[1] = (_Float16)r5;
    o2[2] = (_Float16)r6; o2[3] = (_Float16)r7;
    *(h16x4*)(oH + (size_t)wid*HC + lane*VEC + 4) = o2;
  }
}

// ---------------- pooling (fp16 input) + fused final/FC ----------------
__global__ void k_pool_partial(const _Float16* __restrict__ h, const int* __restrict__ bs,
                               float* __restrict__ psum, float* __restrict__ pmax){
  int b = blockIdx.x, ch = blockIdx.y;
  int f = threadIdx.x;
  int s = bs[b], e = bs[b+1];
  long long len = e - s;
  int i0 = s + (int)(len * ch / 8);
  int i1 = s + (int)(len * (ch+1) / 8);
  float sm = 0.f, mx = -3.0e38f;
  for (int i = i0; i < i1; ++i){
    float v = (float)h[(size_t)i*512 + f];
    sm += v; mx = fmaxf(mx, v);
  }
  int idx = (b*8 + ch)*512 + f;
  psum[idx] = sm; pmax[idx] = mx;
}

__global__ __launch_bounds__(256)
void k_fc(const float* __restrict__ psum, const float* __restrict__ pmax,
          const int* __restrict__ bs, const float* __restrict__ fcW,
          const float* __restrict__ fcb, float* __restrict__ out){
  __shared__ float gs[1024];
  __shared__ float red[4][64];
  int b = blockIdx.x, t = threadIdx.x;
  int o0 = blockIdx.y * 64;
  int cntb = bs[b+1] - bs[b];
  float inv = 1.f / fmaxf((float)cntb, 1.f);
  for (int i = t; i < 512; i += 256){
    float sm = 0.f, mx = -3.0e38f;
    #pragma unroll
    for (int c = 0; c < 8; ++c){
      int idx = (b*8 + c)*512 + i;
      sm += psum[idx]; mx = fmaxf(mx, pmax[idx]);
    }
    gs[i] = sm * inv;
    gs[512 + i] = (mx > -1e37f) ? mx : 0.f;
  }
  __syncthreads();
  int ol = t & 63, q = t >> 6;
  const float* wp = fcW + (size_t)(q*256)*512 + o0 + ol;
  float acc = 0.f;
  #pragma unroll 8
  for (int k = 0; k < 256; ++k)
    acc = fmaf(gs[q*256 + k], wp[(size_t)k*512], acc);
  red[q][ol] = acc;
  __syncthreads();
  if (t < 64){
    float r = red[0][t] + red[1][t] + red[2][t] + red[3][t] + fcb[o0 + t];
    out[b*512 + o0 + t] = r;
  }
}

// ---------------- launcher ----------------
extern "C" void kernel_launch(void* const* d_in, const int* in_sizes, int n_in,
                              void* d_out, int out_size, void* d_ws, size_t ws_size,
                              hipStream_t stream){
  (void)n_in; (void)out_size; (void)ws_size;
  const float* x     = (const float*)d_in[0];
  const int*   ei    = (const int*)d_in[1];
  const int*   batch = (const int*)d_in[2];
  const float* W[4]   = {(const float*)d_in[3],(const float*)d_in[7],(const float*)d_in[11],(const float*)d_in[15]};
  const float* asr[4] = {(const float*)d_in[4],(const float*)d_in[8],(const float*)d_in[12],(const float*)d_in[16]};
  const float* adt[4] = {(const float*)d_in[5],(const float*)d_in[9],(const float*)d_in[13],(const float*)d_in[17]};
  const float* bb[4]  = {(const float*)d_in[6],(const float*)d_in[10],(const float*)d_in[14],(const float*)d_in[18]};
  const float* fcW = (const float*)d_in[19];
  const float* fcb = (const float*)d_in[20];

  const int N  = in_sizes[0] / 128;
  const int E  = in_sizes[1] / 2;
  const int EN = E + N;
  const int B  = 32;
  const int NB = (N + 1023) / 1024;

  char* p = (char*)d_ws;
  auto alloc = [&](size_t bytes){ void* r = (void*)p; p += (bytes + 255) & ~(size_t)255; return r; };
  _Float16* hA = (_Float16*)alloc((size_t)N*512*2);        // GEMM out (gather input)
  _Float16* hB = (_Float16*)alloc((size_t)N*512*2);        // agg out (next GEMM A / pool input)
  _Float16* Wh = (_Float16*)alloc((size_t)294912*2);       // all W^T f16, packed
  float* a2   = (float*)alloc((size_t)N*8*4);              // as4 | ad4
  float* as4 = a2;
  float* ad4 = a2 + (size_t)N*4;
  int*   cntdone = (int*)alloc((size_t)(N+64)*4);          // cnt[N] + done[1]
  int*   cnt  = cntdone;
  int*   done = cntdone + N;
  int*   rp   = (int*)alloc((size_t)(N+1)*4);
  int*   cur  = (int*)alloc((size_t)N*4);
  int*   es   = (int*)alloc((size_t)EN*4);
  int*   bs   = (int*)alloc((size_t)(B+1)*4);
  int*   bsum = (int*)alloc((size_t)64*4);
  float* psum = (float*)alloc((size_t)B*8*512*4);
  float* pmax = (float*)alloc((size_t)B*8*512*4);

  hipMemsetAsync(cntdone, 0, (size_t)(N+1)*4, stream);

  const int CB = (EN + 255)/256;
  const int XB = (N*32 + 255)/256;
  const int WB = (294912 + 255)/256;
  k_front<<<CB + XB + WB + 1, 256, 0, stream>>>(ei, E, N, cnt, x, hB,
                                                W[0], W[1], W[2], W[3], Wh,
                                                batch, B, bs, CB, XB, WB);

  k_scan1<<<NB, 1024, 0, stream>>>(cnt, rp, bsum, done, N, NB);
  k_scan3<<<NB, 1024, 0, stream>>>(rp, cur, bsum, N);
  k_fill<<<(EN+255)/256, 256, 0, stream>>>(ei, E, N, cur, es);

  const int wgrid = (N + 3) / 4;
  const int Kd[4]  = {128, 256, 256, 256};
  const int HCd[4] = {256, 256, 256, 512};
  const size_t Woff[4] = {0, 32768, 98304, 163840};

  for (int L = 0; L < 4; ++L){
    const int K = Kd[L], Nc = HCd[L];
    dim3 gg((N + 63)/64, Nc/128);
    if (Nc == 256)
      k_gemm_fused<64><<<gg, 256, 0, stream>>>(hB, Wh + Woff[L], hA, asr[L], adt[L], as4, ad4, N, K, Nc);
    else
      k_gemm_fused<128><<<gg, 256, 0, stream>>>(hB, Wh + Woff[L], hA, asr[L], adt[L], as4, ad4, N, K, Nc);
    if (Nc == 256)
      k_agg_h<256><<<wgrid, 256, 0, stream>>>(rp, es, as4, ad4, hA, bb[L], hB, N);
    else
      k_agg_h<512><<<wgrid, 256, 0, stream>>>(rp, es, as4, ad4, hA, bb[L], hB, N);
  }

  dim3 pg(B, 8);
  k_pool_partial<<<pg, 512, 0, stream>>>(hB, bs, psum, pmax);
  dim3 fg(B, 8);
  k_fc<<<fg, 256, 0, stream>>>(psum, pmax, bs, fcW, fcb, (float*)d_out);
}